// Round 8
// baseline (357.856 us; speedup 1.0000x reference)
//
#include <hip/hip_runtime.h>

// ScaledConvolutionalDotProduct: B=4, S=2048, D=1024
//   qp = relu(q@Wq + bq); kp = relu(k@Wk + bk); vp = relu(v@Wv + bv)
//   logits = relu(qp@kp^T)/32 + mask;  out = relu(logits@vp)
// Round 8: byte-reduction round.
//   - projf: fp32->bf16 conversion fused into A-staging (kills cvt3, -144MB)
//   - by-fastest XCD ordering (A-panel fetched once per XCD)
//   - mask pre-converted to bf16 (halves mask traffic)
//   - scores/PV keep r7-proven gemm3b core

#define B_ 4
#define S_ 2048
#define D_ 1024

typedef __attribute__((ext_vector_type(8))) short short8;
typedef __attribute__((ext_vector_type(4))) short short4v;
typedef __attribute__((ext_vector_type(4))) float f32x4;
typedef const __attribute__((address_space(1))) void* gas1;
typedef __attribute__((address_space(3))) void* las3;

static __device__ __forceinline__ short f2bf(float x) {
    union { float f; unsigned u; } un; un.f = x;
    unsigned r = un.u + 0x7fff + ((un.u >> 16) & 1);
    return (short)(r >> 16);
}
static __device__ __forceinline__ float bf2f(short s) {
    union { unsigned u; float f; } un; un.u = ((unsigned)(unsigned short)s) << 16;
    return un.f;
}

// ---------------- W [d][e] fp32 -> W^T [e][d] bf16 ----------------
__global__ void make_wT_kernel(const float* __restrict__ Wq, const float* __restrict__ Wk,
                               const float* __restrict__ Wv, short* __restrict__ wT) {
    const float* W = (blockIdx.z == 0) ? Wq : ((blockIdx.z == 1) ? Wk : Wv);
    short* o = wT + (size_t)blockIdx.z * D_ * D_;
    __shared__ float t[32][33];
    int bx = blockIdx.x, by = blockIdx.y;
    int tx = threadIdx.x & 31, ty = threadIdx.x >> 5;   // 32 x 8
    #pragma unroll
    for (int r = ty; r < 32; r += 8)
        t[r][tx] = W[(size_t)(by * 32 + r) * D_ + bx * 32 + tx];
    __syncthreads();
    #pragma unroll
    for (int r = ty; r < 32; r += 8)
        o[(size_t)(bx * 32 + r) * D_ + by * 32 + tx] = f2bf(t[tx][r]);
}

// ---------------- mask f32 -> bf16 ----------------
__global__ void make_maskbf_kernel(const float* __restrict__ mask, short* __restrict__ mb) {
    size_t i = ((size_t)blockIdx.x * blockDim.x + threadIdx.x) * 8;
    float4 a = *(const float4*)(mask + i);
    float4 b = *(const float4*)(mask + i + 4);
    short8 r;
    r[0] = f2bf(a.x); r[1] = f2bf(a.y); r[2] = f2bf(a.z); r[3] = f2bf(a.w);
    r[4] = f2bf(b.x); r[5] = f2bf(b.y); r[6] = f2bf(b.z); r[7] = f2bf(b.w);
    *(short8*)(mb + i) = r;
}

// ---------------- vp [b][s][e] -> vpT [b][e][s] (bf16) ----------------
__global__ void transpose_bf16_kernel(const short* __restrict__ in, short* __restrict__ out) {
    __shared__ short t[64][65];
    int b = blockIdx.z;
    int e0 = blockIdx.x * 64, s0 = blockIdx.y * 64;
    const short* src = in + (size_t)b * S_ * D_;
    short* dst = out + (size_t)b * D_ * S_;
    int tx = threadIdx.x & 63, ty = threadIdx.x >> 6;   // 64 x 4
    #pragma unroll
    for (int r = ty; r < 64; r += 4)
        t[r][tx] = src[(size_t)(s0 + r) * D_ + e0 + tx];
    __syncthreads();
    #pragma unroll
    for (int r = ty; r < 64; r += 4)
        dst[(size_t)(e0 + r) * S_ + s0 + tx] = t[tx][r];
}

// =====================================================================
// projf: qp/kp/vp = relu(x_f32 @ W + b), x converted to bf16 in-staging.
// BM=256 BN=128 BK=32, 8 waves (4x2), double-buffered LDS (48KB).
// A path: f32 global->regs (2-tile-deep prefetch) -> cvt -> swizzled ds_write_b64.
// B path: global_load_lds (source-swizzled).
// vmcnt bookkeeping (steady, t <= NT-3):
//   entering tile t: outstanding = [A(t+1)x4]
//   phA issues glB(t+1) then (sched-pinned) A(t+2)x4  -> 9 outstanding
//   phB: vmcnt(5) retires A(t+1)x4; write A(t+1)->p^1; lgkm0;
//        vmcnt(4) retires glB(t+1); barrier  -> invariant restored.
// Tails: t==NT-2 -> vmcnt(1)/vmcnt(0); t==NT-1 -> no staging.
// =====================================================================
__global__ __launch_bounds__(512, 2)
void projf_kernel(const float* __restrict__ q, const float* __restrict__ k,
                  const float* __restrict__ v, const short* __restrict__ wT,
                  short* __restrict__ outp,
                  const float* __restrict__ bq, const float* __restrict__ bk,
                  const float* __restrict__ bv) {
    constexpr int NT = D_ / 32;              // 32 K-tiles
    __shared__ short As[2][256 * 32];
    __shared__ short Bs[2][128 * 32];

    // XCD chunk + by-fastest decode (gx=32, gy=8, gz=3; nwg=768)
    const int gx = 32, gy = 8;
    const int nwg = 768;
    const int flat = blockIdx.x + gx * (blockIdx.y + gy * blockIdx.z);
    const int swz = (flat & 7) * (nwg >> 3) + (flat >> 3);
    const int by = swz % gy;
    const int rem = swz / gy;
    const int bx = rem % gx;
    const int bz = rem / gx;

    const float* Af = (bz == 0) ? q : ((bz == 1) ? k : v);
    const short* Bb = wT + (size_t)bz * D_ * D_;
    const float* bias = (bz == 0) ? bq : ((bz == 1) ? bk : bv);
    short* Cs = outp + (size_t)bz * ((size_t)B_ * S_ * D_);

    const int m0 = bx * 256, n0 = by * 128;
    const int tid = threadIdx.x;
    const int lane = tid & 63;
    const int w = tid >> 6;
    const int wr = w >> 1, wc = w & 1;       // 4 x 2 wave grid
    const int lr16 = lane & 15, kq = lane >> 4;

    // B source-side inverse swizzle (16B slots within 64B rows)
    const int csrcB = (((tid & 3) ^ ((tid >> 3) & 3)) << 3);
    auto stageBgl = [&](int buf, int kt) {
        int row = tid >> 2;
        const short* src = Bb + (size_t)(n0 + row) * D_ + kt * 32 + csrcB;
        __builtin_amdgcn_global_load_lds((gas1)src, (las3)&Bs[buf][tid * 8], 16, 0, 0);
    };
    // A f32 loads: 4 rounds of 64 rows; thread covers row R*64+(tid>>3), chunk tid&7 (4 f32)
    auto ldgA = [&](float4* aw, int kt) {
        #pragma unroll
        for (int R = 0; R < 4; ++R) {
            int row = R * 64 + (tid >> 3);
            aw[R] = *(const float4*)(Af + (size_t)(m0 + row) * D_ + kt * 32 + (tid & 7) * 4);
        }
    };
    // cvt + swizzled ds_write_b64: original slot c>>1 -> physical (c>>1)^((row>>1)&3)
    auto dswriteA = [&](int buf, const float4* aw) {
        #pragma unroll
        for (int R = 0; R < 4; ++R) {
            int row = R * 64 + (tid >> 3);
            int c = tid & 7;
            int slot = (c >> 1) ^ ((row >> 1) & 3);
            short4v s;
            s[0] = f2bf(aw[R].x); s[1] = f2bf(aw[R].y);
            s[2] = f2bf(aw[R].z); s[3] = f2bf(aw[R].w);
            *(short4v*)&As[buf][row * 32 + slot * 8 + (c & 1) * 4] = s;
        }
    };
    auto ldA = [&](int buf, int mi) -> short8 {
        int row = wr * 64 + mi * 16 + lr16;
        int col = (kq ^ ((row >> 1) & 3)) << 3;
        return *(const short8*)&As[buf][row * 32 + col];
    };
    auto ldB = [&](int buf, int ni) -> short8 {
        int row = wc * 64 + ni * 16 + lr16;
        int col = (kq ^ ((row >> 1) & 3)) << 3;
        return *(const short8*)&Bs[buf][row * 32 + col];
    };

    f32x4 acc[4][4] = {};
    float4 s0a[4], s1a[4];

    // prologue: glB(0)->b0 first (so vmcnt(4) retires it + A(0))
    stageBgl(0, 0);
    __builtin_amdgcn_sched_barrier(0);
    ldgA(s0a, 0);                            // A(0)
    __builtin_amdgcn_sched_barrier(0);
    ldgA(s1a, 1);                            // A(1)
    asm volatile("s_waitcnt vmcnt(4)" ::: "memory");   // glB0 + A(0) done
    dswriteA(0, s0a);
    asm volatile("s_waitcnt lgkmcnt(0)" ::: "memory");
    __builtin_amdgcn_s_barrier();
    // outstanding: [A(1)x4]

    auto tileBody = [&](int t, float4* awWr, float4* awLd) {
        const int p = t & 1;
        // ---- phase A ----
        short8 a0 = ldA(p, 0), a1 = ldA(p, 1);
        short8 b0 = ldB(p, 0), b1 = ldB(p, 1), b2 = ldB(p, 2), b3 = ldB(p, 3);
        if (t + 1 < NT) stageBgl(p ^ 1, t + 1);
        __builtin_amdgcn_sched_barrier(0);
        if (t + 2 < NT) ldgA(awLd, t + 2);
        asm volatile("s_waitcnt lgkmcnt(0)" ::: "memory");
        __builtin_amdgcn_s_setprio(1);
        acc[0][0] = __builtin_amdgcn_mfma_f32_16x16x32_bf16(a0, b0, acc[0][0], 0, 0, 0);
        acc[0][1] = __builtin_amdgcn_mfma_f32_16x16x32_bf16(a0, b1, acc[0][1], 0, 0, 0);
        acc[0][2] = __builtin_amdgcn_mfma_f32_16x16x32_bf16(a0, b2, acc[0][2], 0, 0, 0);
        acc[0][3] = __builtin_amdgcn_mfma_f32_16x16x32_bf16(a0, b3, acc[0][3], 0, 0, 0);
        acc[1][0] = __builtin_amdgcn_mfma_f32_16x16x32_bf16(a1, b0, acc[1][0], 0, 0, 0);
        acc[1][1] = __builtin_amdgcn_mfma_f32_16x16x32_bf16(a1, b1, acc[1][1], 0, 0, 0);
        acc[1][2] = __builtin_amdgcn_mfma_f32_16x16x32_bf16(a1, b2, acc[1][2], 0, 0, 0);
        acc[1][3] = __builtin_amdgcn_mfma_f32_16x16x32_bf16(a1, b3, acc[1][3], 0, 0, 0);
        __builtin_amdgcn_s_setprio(0);
        __builtin_amdgcn_s_barrier();
        // ---- phase B ----
        short8 a2 = ldA(p, 2), a3 = ldA(p, 3);
        asm volatile("s_waitcnt lgkmcnt(0)" ::: "memory");
        __builtin_amdgcn_s_setprio(1);
        acc[2][0] = __builtin_amdgcn_mfma_f32_16x16x32_bf16(a2, b0, acc[2][0], 0, 0, 0);
        acc[2][1] = __builtin_amdgcn_mfma_f32_16x16x32_bf16(a2, b1, acc[2][1], 0, 0, 0);
        acc[2][2] = __builtin_amdgcn_mfma_f32_16x16x32_bf16(a2, b2, acc[2][2], 0, 0, 0);
        acc[2][3] = __builtin_amdgcn_mfma_f32_16x16x32_bf16(a2, b3, acc[2][3], 0, 0, 0);
        acc[3][0] = __builtin_amdgcn_mfma_f32_16x16x32_bf16(a3, b0, acc[3][0], 0, 0, 0);
        acc[3][1] = __builtin_amdgcn_mfma_f32_16x16x32_bf16(a3, b1, acc[3][1], 0, 0, 0);
        acc[3][2] = __builtin_amdgcn_mfma_f32_16x16x32_bf16(a3, b2, acc[3][2], 0, 0, 0);
        acc[3][3] = __builtin_amdgcn_mfma_f32_16x16x32_bf16(a3, b3, acc[3][3], 0, 0, 0);
        __builtin_amdgcn_s_setprio(0);
        // retire A(t+1) so we can write it to LDS
        if (t < NT - 2)       asm volatile("s_waitcnt vmcnt(5)" ::: "memory");
        else if (t == NT - 2) asm volatile("s_waitcnt vmcnt(1)" ::: "memory");
        if (t + 1 < NT) {
            dswriteA(p ^ 1, awWr);
            asm volatile("s_waitcnt lgkmcnt(0)" ::: "memory");
        }
        // retire glB(t+1) before next tile's reads
        if (t < NT - 2)       asm volatile("s_waitcnt vmcnt(4)" ::: "memory");
        else if (t == NT - 2) asm volatile("s_waitcnt vmcnt(0)" ::: "memory");
        __builtin_amdgcn_s_barrier();
    };

    #pragma unroll 1
    for (int I = 0; I < NT / 2; ++I) {
        tileBody(2 * I,     s1a, s0a);   // write A(2I+1) from s1, load A(2I+2) into s0
        tileBody(2 * I + 1, s0a, s1a);   // write A(2I+2) from s0, load A(2I+3) into s1
    }

    // epilogue: relu(acc + bias[n]) -> bf16
    #pragma unroll
    for (int mi = 0; mi < 4; ++mi) {
        #pragma unroll
        for (int ni = 0; ni < 4; ++ni) {
            int n = n0 + wc * 64 + ni * 16 + lr16;
            int mb = m0 + wr * 64 + mi * 16 + kq * 4;
            #pragma unroll
            for (int j = 0; j < 4; ++j) {
                float val = fmaxf(acc[mi][ni][j] + bias[n], 0.f);
                Cs[(size_t)(mb + j) * D_ + n] = f2bf(val);
            }
        }
    }
}

// -------- triple-buffered BK=32 GEMM (r7-proven core): C = epi(A * B^T) --------
// 8 waves 4x2, BM=256 BN=128, 72KB LDS -> 2 blocks/CU, counted vmcnt(3).
// EPI 1: bf16 = relu(acc)/32 + maskbf[m][n];  EPI 2: f32 = relu(acc)
template <int EPI>
__global__ __launch_bounds__(512, 2)
void gemm3b_kernel(const short* __restrict__ A, const short* __restrict__ B, void* __restrict__ Cv,
                   int K, int lda, int ldb, int ldc,
                   size_t sA, size_t sB, size_t sC,
                   const short* __restrict__ maskb, int ldmask) {
    constexpr int BM = 256, BN = 128;
    __shared__ short As[3][BM * 32];
    __shared__ short Bs[3][BN * 32];

    // XCD chunk + by-fastest decode (A-panel reuse on one XCD)
    const int gx = gridDim.x, gy = gridDim.y;
    const int nwg = gx * gy * gridDim.z;
    const int flat = blockIdx.x + gx * (blockIdx.y + gy * blockIdx.z);
    const int swz = (flat & 7) * (nwg >> 3) + (flat >> 3);
    const int by = swz % gy;
    const int rem = swz / gy;
    const int bx = rem % gx;
    const int bz = rem / gx;

    const int m0 = bx * BM, n0 = by * BN;
    const short* Ab = A + (size_t)bz * sA;
    const short* Bb = B + (size_t)bz * sB;

    const int tid = threadIdx.x;
    const int lane = tid & 63;
    const int w = tid >> 6;
    const int wr = w >> 1, wc = w & 1;       // 4 x 2 wave grid
    const int lr16 = lane & 15, kq = lane >> 4;
    const int NT = K >> 5;

    const int csrc = (((tid & 3) ^ ((tid >> 3) & 3)) << 3);

    auto stageA = [&](int buf, int kt) {
        if (kt >= NT) return;
        #pragma unroll
        for (int R = 0; R < 2; ++R) {
            int row = R * 128 + (tid >> 2);
            const short* src = Ab + (size_t)(m0 + row) * lda + kt * 32 + csrc;
            __builtin_amdgcn_global_load_lds((gas1)src, (las3)&As[buf][R * 4096 + tid * 8], 16, 0, 0);
        }
    };
    auto stageB = [&](int buf, int kt) {
        if (kt >= NT) return;
        int row = tid >> 2;
        const short* src = Bb + (size_t)(n0 + row) * ldb + kt * 32 + csrc;
        __builtin_amdgcn_global_load_lds((gas1)src, (las3)&Bs[buf][tid * 8], 16, 0, 0);
    };
    auto ldA = [&](int buf, int mi) -> short8 {
        int row = wr * 64 + mi * 16 + lr16;
        int col = (kq ^ ((row >> 1) & 3)) << 3;
        return *(const short8*)&As[buf][row * 32 + col];
    };
    auto ldB = [&](int buf, int ni) -> short8 {
        int row = wc * 64 + ni * 16 + lr16;
        int col = (kq ^ ((row >> 1) & 3)) << 3;
        return *(const short8*)&Bs[buf][row * 32 + col];
    };

    f32x4 acc[4][4] = {};

    stageA(0, 0); stageB(0, 0);
    stageA(1, 1); stageB(1, 1);
    asm volatile("s_waitcnt vmcnt(3)" ::: "memory");
    __builtin_amdgcn_s_barrier();

    int r0 = 0, r1 = 1, r2 = 2;
    #pragma unroll 1
    for (int t = 0; t < NT; ++t) {
        short8 a0 = ldA(r0, 0), a1 = ldA(r0, 1);
        short8 b0 = ldB(r0, 0), b1 = ldB(r0, 1), b2 = ldB(r0, 2), b3 = ldB(r0, 3);
        stageA(r2, t + 2);
        asm volatile("s_waitcnt lgkmcnt(0)" ::: "memory");
        __builtin_amdgcn_s_setprio(1);
        acc[0][0] = __builtin_amdgcn_mfma_f32_16x16x32_bf16(a0, b0, acc[0][0], 0, 0, 0);
        acc[0][1] = __builtin_amdgcn_mfma_f32_16x16x32_bf16(a0, b1, acc[0][1], 0, 0, 0);
        acc[0][2] = __builtin_amdgcn_mfma_f32_16x16x32_bf16(a0, b2, acc[0][2], 0, 0, 0);
        acc[0][3] = __builtin_amdgcn_mfma_f32_16x16x32_bf16(a0, b3, acc[0][3], 0, 0, 0);
        acc[1][0] = __builtin_amdgcn_mfma_f32_16x16x32_bf16(a1, b0, acc[1][0], 0, 0, 0);
        acc[1][1] = __builtin_amdgcn_mfma_f32_16x16x32_bf16(a1, b1, acc[1][1], 0, 0, 0);
        acc[1][2] = __builtin_amdgcn_mfma_f32_16x16x32_bf16(a1, b2, acc[1][2], 0, 0, 0);
        acc[1][3] = __builtin_amdgcn_mfma_f32_16x16x32_bf16(a1, b3, acc[1][3], 0, 0, 0);
        __builtin_amdgcn_s_setprio(0);
        __builtin_amdgcn_s_barrier();

        short8 a2 = ldA(r0, 2), a3 = ldA(r0, 3);
        stageB(r2, t + 2);
        asm volatile("s_waitcnt lgkmcnt(0)" ::: "memory");
        __builtin_amdgcn_s_setprio(1);
        acc[2][0] = __builtin_amdgcn_mfma_f32_16x16x32_bf16(a2, b0, acc[2][0], 0, 0, 0);
        acc[2][1] = __builtin_amdgcn_mfma_f32_16x16x32_bf16(a2, b1, acc[2][1], 0, 0, 0);
        acc[2][2] = __builtin_amdgcn_mfma_f32_16x16x32_bf16(a2, b2, acc[2][2], 0, 0, 0);
        acc[2][3] = __builtin_amdgcn_mfma_f32_16x16x32_bf16(a2, b3, acc[2][3], 0, 0, 0);
        acc[3][0] = __builtin_amdgcn_mfma_f32_16x16x32_bf16(a3, b0, acc[3][0], 0, 0, 0);
        acc[3][1] = __builtin_amdgcn_mfma_f32_16x16x32_bf16(a3, b1, acc[3][1], 0, 0, 0);
        acc[3][2] = __builtin_amdgcn_mfma_f32_16x16x32_bf16(a3, b2, acc[3][2], 0, 0, 0);
        acc[3][3] = __builtin_amdgcn_mfma_f32_16x16x32_bf16(a3, b3, acc[3][3], 0, 0, 0);
        __builtin_amdgcn_s_setprio(0);
        asm volatile("s_waitcnt vmcnt(3)" ::: "memory");
        __builtin_amdgcn_s_barrier();

        int tmp = r0; r0 = r1; r1 = r2; r2 = tmp;
    }

    short* Cs = (short*)Cv + (size_t)bz * sC;
    float* Cf = (float*)Cv + (size_t)bz * sC;
    #pragma unroll
    for (int mi = 0; mi < 4; ++mi) {
        #pragma unroll
        for (int ni = 0; ni < 4; ++ni) {
            int n = n0 + wc * 64 + ni * 16 + lr16;
            int mb = m0 + wr * 64 + mi * 16 + kq * 4;
            #pragma unroll
            for (int j = 0; j < 4; ++j) {
                int m = mb + j;
                float val = acc[mi][ni][j];
                if constexpr (EPI == 1) {
                    val = fmaxf(val, 0.f) * 0.03125f + bf2f(maskb[(size_t)m * ldmask + n]);
                    Cs[(size_t)m * ldc + n] = f2bf(val);
                } else {
                    Cf[(size_t)m * ldc + n] = fmaxf(val, 0.f);
                }
            }
        }
    }
}

extern "C" void kernel_launch(void* const* d_in, const int* in_sizes, int n_in,
                              void* d_out, int out_size, void* d_ws, size_t ws_size,
                              hipStream_t stream) {
    const float* q    = (const float*)d_in[0];
    const float* k    = (const float*)d_in[1];
    const float* v    = (const float*)d_in[2];
    const float* mask = (const float*)d_in[3];
    const float* Wq   = (const float*)d_in[4];
    const float* Wk   = (const float*)d_in[5];
    const float* Wv   = (const float*)d_in[6];
    const float* bq   = (const float*)d_in[7];
    const float* bk   = (const float*)d_in[8];
    const float* bv   = (const float*)d_in[9];
    float* out = (float*)d_out;

    char* ws = (char*)d_ws;
    // layout (bytes):
    //   wT     @ 0          : 3*1024*1024*2 = 6,291,456
    //   maskbf @ 6,291,456  : 2048*2048*2   = 8,388,608
    //   qkvp   @ 14,680,064 : 3*8192*1024*2 = 50,331,648  (qp|kp|vp)
    //   logits @ 65,011,712 : 4*2048*2048*2 = 33,554,432
    //   vpT    = qp region (qp dead after scores)
    //   total 98,566,144
    short* wT     = (short*)(ws);
    short* maskbf = (short*)(ws + 6291456);
    short* qkvp   = (short*)(ws + 14680064);
    short* qp     = qkvp;
    short* kp     = qkvp + (size_t)B_ * S_ * D_;
    short* vp     = qkvp + 2 * (size_t)B_ * S_ * D_;
    short* logits = (short*)(ws + 65011712);
    short* vpT    = qp;   // overlay (qp dead after scores)

    // 1) W -> W^T bf16; mask -> bf16
    make_wT_kernel<<<dim3(32, 32, 3), 256, 0, stream>>>(Wq, Wk, Wv, wT);
    make_maskbf_kernel<<<(S_ * S_ / 8 / 256), 256, 0, stream>>>(mask, maskbf);

    // 2) projections with fused f32->bf16 A-staging  [M=8192,N=1024,K=1024, z=3]
    projf_kernel<<<dim3(32, 8, 3), 512, 0, stream>>>(q, k, v, wT, qkvp, bq, bk, bv);

    // 3) scores: logits = relu(qp@kp^T)/32 + mask   [per-batch M=N=2048,K=1024]
    gemm3b_kernel<1><<<dim3(8, 16, 4), 512, 0, stream>>>(
        qp, kp, logits, D_, D_, D_, S_,
        (size_t)S_ * D_, (size_t)S_ * D_, (size_t)S_ * S_,
        maskbf, S_);

    // 4) vp -> vpT per batch (into qp region, dead after scores)
    transpose_bf16_kernel<<<dim3(D_ / 64, S_ / 64, B_), 256, 0, stream>>>(vp, vpT);

    // 5) PV: out = relu(logits @ vpT^T)   [per-batch M=2048,N=1024,K=2048], f32 out
    gemm3b_kernel<2><<<dim3(8, 8, 4), 512, 0, stream>>>(
        logits, vpT, out, S_, S_, S_, D_,
        (size_t)S_ * S_, (size_t)D_ * S_, (size_t)S_ * D_,
        nullptr, 0);
}